// Round 8
// baseline (2054.125 us; speedup 1.0000x reference)
//
#include <hip/hip_runtime.h>
#include <hip/hip_bf16.h>

typedef __attribute__((ext_vector_type(8))) short bf16x8;
typedef __attribute__((ext_vector_type(4))) float f32x4;
typedef __attribute__((ext_vector_type(4))) unsigned short u16x4;
typedef __attribute__((ext_vector_type(8))) unsigned short u16x8;

#define SEQ   4096
#define DIM   1024
#define MTOT  16384
#define NTILE 32            // SEQ/128 query tiles (128-granular packing)
#define NTRI  528           // causal 128-tiles per batch
#define TSZ   16384         // elems per 128x128 tile
#define PSIZE ((size_t)NTRI * TSZ)   // 16.5 MiB per batch (u16)

#define AS1 __attribute__((address_space(1)))
#define AS3 __attribute__((address_space(3)))

static __device__ __forceinline__ unsigned short f2bf(float f) {
  union { float f; unsigned u; } v; v.f = f;
  unsigned r = v.u + 0x7FFFu + ((v.u >> 16) & 1u);
  return (unsigned short)(r >> 16);
}

static __device__ __forceinline__ unsigned short f2h(float f) {
  union { _Float16 h; unsigned short u; } v; v.h = (_Float16)f; return v.u;
}

static __device__ __forceinline__ float h2f(unsigned short u) {
  union { unsigned short u; _Float16 h; } v; v.u = u; return (float)v.h;
}

static __device__ __forceinline__ bf16x8 pack8(f32x4 a, f32x4 b) {
  bf16x8 v;
  v[0]=(short)f2bf(a[0]); v[1]=(short)f2bf(a[1]);
  v[2]=(short)f2bf(a[2]); v[3]=(short)f2bf(a[3]);
  v[4]=(short)f2bf(b[0]); v[5]=(short)f2bf(b[1]);
  v[6]=(short)f2bf(b[2]); v[7]=(short)f2bf(b[3]);
  return v;
}

static __device__ __forceinline__ int tri_row(int id) {
  int ti = (int)((sqrtf(8.f * (float)id + 1.f) - 1.f) * 0.5f);
  while ((ti + 1) * (ti + 2) / 2 <= id) ++ti;
  while (ti * (ti + 1) / 2 > id) --ti;
  return ti;
}

// ---------------- fused fp32 -> bf16 preconvert (x + all 3 weights) ---------
__global__ __launch_bounds__(256) void conv_all(
    const float* __restrict__ x,
    const float* __restrict__ Wq, const float* __restrict__ Wk,
    const float* __restrict__ Wv,
    unsigned short* __restrict__ xb, unsigned short* __restrict__ Wb)
{
  const int bid = blockIdx.x;
  if (bid < 8192) {
    const int i = bid * 256 + threadIdx.x;      // x: 2097152 vec8
    const f32x4* s = (const f32x4*)(x + (size_t)i * 8);
    f32x4 a = s[0], b = s[1];
    *(bf16x8*)(xb + (size_t)i * 8) = pack8(a, b);
  } else {
    const int i = (bid - 8192) * 256 + threadIdx.x;   // weights: 393216 vec8
    const int seg = i >> 17;
    const int loc = i & 131071;
    const float* src = (seg == 0) ? Wq : (seg == 1) ? Wk : Wv;
    const float scale = (seg == 0) ? 0.03125f : 1.0f;  // fold 1/sqrt(D) into Wq
    const f32x4* s = (const f32x4*)(src + (size_t)loc * 8);
    f32x4 a = s[0], b = s[1];
#pragma unroll
    for (int r = 0; r < 4; ++r) { a[r] *= scale; b[r] *= scale; }
    *(bf16x8*)(Wb + (size_t)i * 8) = pack8(a, b);
  }
}

// ---------------- counted-vmcnt heads ----------------
static __device__ __forceinline__ void head_n4(bool more) {
  if (more) asm volatile("s_waitcnt vmcnt(4)" ::: "memory");
  else      asm volatile("s_waitcnt vmcnt(0)" ::: "memory");
  __builtin_amdgcn_s_barrier();
  asm volatile("" ::: "memory");
}
static __device__ __forceinline__ void head_n8(bool more) {
  if (more) asm volatile("s_waitcnt vmcnt(8)" ::: "memory");
  else      asm volatile("s_waitcnt vmcnt(0)" ::: "memory");
  __builtin_amdgcn_s_barrier();
  asm volatile("" ::: "memory");
}
static __device__ __forceinline__ void tail_bar() {
  asm volatile("" ::: "memory");
  __builtin_amdgcn_s_barrier();
  asm volatile("" ::: "memory");
}

// ============================================================================
// QKV: 256x256 tile, 1024 thr / 16 waves (4x4), BK=64 (r6 structure, 135us).
// z=2 (V) uses operand-SWAPPED MFMA so the output is V^T directly:
// mfma(bq, af) -> D-row = W-row (e), D-col = x-row (s). Stores become
// l15-consecutive (32B segments) instead of 8KB-stride 8B scatters.
// ============================================================================
static __device__ __forceinline__ void stage64(
    const unsigned short* __restrict__ g, int ld, unsigned short* dst, int tid)
{
  const int w = tid >> 6, ln = tid & 63;
#pragma unroll
  for (int l = 0; l < 2; ++l) {
    const int row = l * 128 + w * 8 + (ln >> 3);
    const int grp = (ln & 7) ^ (row & 7);
    __builtin_amdgcn_global_load_lds(
        (const AS1 void*)(g + (size_t)row * ld + grp * 8),
        (AS3 void*)&dst[(l * 128 + w * 8) * 64], 16, 0, 0);
  }
}

template<bool SWP>
static __device__ __forceinline__ void compute64(
    const unsigned short* Au, const unsigned short* Bu,
    int wr, int wc, int l15, int quad, f32x4 (&acc)[4][4])
{
#pragma unroll
  for (int ks = 0; ks < 2; ++ks) {
    bf16x8 af[4], bq[4];
#pragma unroll
    for (int i = 0; i < 4; ++i) {
      const int ar = wr * 64 + i * 16 + l15;
      af[i] = *(const bf16x8*)&Au[ar * 64 + (((ks * 4 + quad) ^ (ar & 7)) * 8)];
      const int br = wc * 64 + i * 16 + l15;
      bq[i] = *(const bf16x8*)&Bu[br * 64 + (((ks * 4 + quad) ^ (br & 7)) * 8)];
    }
    __builtin_amdgcn_s_setprio(1);
#pragma unroll
    for (int i = 0; i < 4; ++i)
#pragma unroll
      for (int j = 0; j < 4; ++j) {
        if (!SWP)
          acc[i][j] = __builtin_amdgcn_mfma_f32_16x16x32_bf16(af[i], bq[j], acc[i][j], 0, 0, 0);
        else   // acc[i][j]: rows = B-frag i (W-row e), cols = A-frag j (x-row s)
          acc[i][j] = __builtin_amdgcn_mfma_f32_16x16x32_bf16(bq[i], af[j], acc[i][j], 0, 0, 0);
      }
    __builtin_amdgcn_s_setprio(0);
  }
}

__global__ __launch_bounds__(1024, 4) void qkv_gemm5(
    const unsigned short* __restrict__ xb,
    const unsigned short* __restrict__ Wb,
    unsigned short* __restrict__ outQ)
{
  __shared__ unsigned short As[2][256 * 64];
  __shared__ unsigned short Bs[2][256 * 64];

  const int bid = blockIdx.x;               // 256
  const int xcd = bid & 7, i = bid >> 3;
  const int mt = xcd * 8 + (i >> 2);        // A-panel locality per XCD
  const int nt = i & 3;
  const int m0 = mt * 256, n0 = nt * 256;

  const int tid = threadIdx.x;
  const int w = tid >> 6, ln = tid & 63;
  const int l15 = ln & 15, quad = ln >> 4;
  const int wr = w >> 2, wc = w & 3;

  const unsigned short* Abase = xb + (size_t)m0 * DIM;
  auto gA = [&](int v) { return Abase + (v & 15) * 64; };
  auto gB = [&](int v) {
    return Wb + (size_t)(v >> 4) * (DIM * DIM) + (size_t)n0 * DIM + (v & 15) * 64;
  };

  f32x4 acc[4][4] = {};

  stage64(gA(0), DIM, As[0], tid);
  stage64(gB(0), DIM, Bs[0], tid);
  stage64(gA(1), DIM, As[1], tid);
  stage64(gB(1), DIM, Bs[1], tid);

#pragma unroll 1
  for (int v = 0; v < 48; ++v) {
    const int p = v & 1;
    head_n4(v + 1 < 48);
    if (v < 32) compute64<false>(As[p], Bs[p], wr, wc, l15, quad, acc);
    else        compute64<true >(As[p], Bs[p], wr, wc, l15, quad, acc);
    tail_bar();

    if ((v & 15) == 15) {
      const int z = v >> 4;
      unsigned short* outb = outQ + (size_t)z * ((size_t)MTOT * DIM);
      if (z < 2) {
#pragma unroll
        for (int fm = 0; fm < 4; ++fm)
#pragma unroll
          for (int fn = 0; fn < 4; ++fn) {
            const int m = m0 + wr * 64 + fm * 16 + quad * 4;
            const int e = n0 + wc * 64 + fn * 16 + l15;
            unsigned short* pp = outb + (size_t)m * DIM + e;
#pragma unroll
            for (int r = 0; r < 4; ++r) pp[(size_t)r * DIM] = f2bf(acc[fm][fn][r]);
          }
      } else {
        // swapped layout: acc[i][j] rows = e (W-row), cols = s (x-row)
        const int bb = m0 >> 12;                  // batch (tile never straddles)
#pragma unroll
        for (int fi = 0; fi < 4; ++fi)
#pragma unroll
          for (int fj = 0; fj < 4; ++fj) {
            const int e  = n0 + wc * 64 + fi * 16 + quad * 4;
            const int ss = (m0 & 4095) + wr * 64 + fj * 16 + l15;
            unsigned short* pp = outb + ((size_t)bb * DIM + e) * SEQ + ss;
#pragma unroll
            for (int r = 0; r < 4; ++r) pp[(size_t)r * SEQ] = f2bf(acc[fi][fj][r]);
          }
      }
#pragma unroll
      for (int fm = 0; fm < 4; ++fm)
#pragma unroll
        for (int fn = 0; fn < 4; ++fn) acc[fm][fn] = (f32x4){0.f, 0.f, 0.f, 0.f};
    }

    if (v + 2 < 48) {
      stage64(gA(v + 2), DIM, As[p], tid);
      stage64(gB(v + 2), DIM, Bs[p], tid);
    }
  }
}

// ============================================================================
// 128x128-tile core, BK=64, counted-vmcnt double buffer (r4-verified).
// LDS 64 KiB -> 2 blocks/CU.
// ============================================================================
static __device__ __forceinline__ void stage128(
    const unsigned short* __restrict__ Ab, int lda,
    const unsigned short* __restrict__ Bb, int ldb,
    unsigned short* Al, unsigned short* Bl, int tid)
{
  const int wv = tid >> 6, ln = tid & 63;
  const int lrow = ln >> 3, lcol = (ln & 7) * 8;
#pragma unroll
  for (int r = 0; r < 4; ++r) {
    const int row = (wv * 4 + r) * 8 + lrow;
    const int sw = ((row >> 2) & 3) << 4;
    __builtin_amdgcn_global_load_lds(
        (const AS1 void*)(Ab + (size_t)row * lda + (lcol ^ sw)),
        (AS3 void*)&Al[(wv * 4 + r) * 512], 16, 0, 0);
    __builtin_amdgcn_global_load_lds(
        (const AS1 void*)(Bb + (size_t)row * ldb + (lcol ^ sw)),
        (AS3 void*)&Bl[(wv * 4 + r) * 512], 16, 0, 0);
  }
}

static __device__ __forceinline__ void compute128(
    const unsigned short* Al, const unsigned short* Bl,
    int mw, int nw, int l15, int quad, f32x4 (&acc)[4][4])
{
  const int csw = (l15 >> 2) << 4;
#pragma unroll
  for (int ks = 0; ks < 2; ++ks) {
    bf16x8 af[4], bfr[4];
#pragma unroll
    for (int i = 0; i < 4; ++i) {
      af[i]  = *(const bf16x8*)&Al[(mw * 64 + i * 16 + l15) * 64 + ((ks * 32 + quad * 8) ^ csw)];
      bfr[i] = *(const bf16x8*)&Bl[(nw * 64 + i * 16 + l15) * 64 + ((ks * 32 + quad * 8) ^ csw)];
    }
    __builtin_amdgcn_s_setprio(1);
#pragma unroll
    for (int mi = 0; mi < 4; ++mi)
#pragma unroll
      for (int ni = 0; ni < 4; ++ni)
        acc[mi][ni] = __builtin_amdgcn_mfma_f32_16x16x32_bf16(af[mi], bfr[ni], acc[mi][ni], 0, 0, 0);
    __builtin_amdgcn_s_setprio(0);
  }
}

static __device__ __forceinline__ void gemm128_pipe(
    const unsigned short* __restrict__ Ab, int lda,
    const unsigned short* __restrict__ Bb, int ldb, int nt,
    unsigned short (*Al)[128 * 64], unsigned short (*Bl)[128 * 64],
    int tid, int mw, int nw, int l15, int quad, f32x4 (&acc)[4][4])
{
  stage128(Ab, lda, Bb, ldb, Al[0], Bl[0], tid);
  if (nt > 1) stage128(Ab + 64, lda, Bb + 64, ldb, Al[1], Bl[1], tid);
#pragma unroll 1
  for (int v = 0; v < nt; ++v) {
    const int p = v & 1;
    head_n8(v + 1 < nt);
    compute128(Al[p], Bl[p], mw, nw, l15, quad, acc);
    tail_bar();
    if (v + 2 < nt)
      stage128(Ab + (v + 2) * 64, lda, Bb + (v + 2) * 64, ldb, Al[p], Bl[p], tid);
  }
}

// S base per (batch, tile-row).  S[b0],S[b1] in ws[0,33MiB); S[b2] in
// out[0,16.5MiB); S[b3] in out[16.5,32MiB) except TI=31 which spills to
// ws[33,34MiB) (dead Wb space).  Ssp is pre-adjusted so Ssp+tri(31)*TSZ
// lands at the spill region.
static __device__ __forceinline__ unsigned short* s_base(
    int b, int ti, unsigned short* Sws, unsigned short* Sout,
    unsigned short* Ssp)
{
  unsigned short* base = (b == 0) ? Sws
                       : (b == 1) ? (Sws + PSIZE)
                       : (b == 2) ? Sout : (Sout + PSIZE);
  if (b == 3 && ti == 31) base = Ssp;
  return base;
}

// ---------------- S = Q K^T: all 4 batches, one launch ----------------------
// 2112 blocks = 8 XCD x 264. Uniform K=1024 per block.
__global__ __launch_bounds__(256) void qk_gemm_p(
    const unsigned short* __restrict__ Q,
    const unsigned short* __restrict__ K,
    unsigned short* __restrict__ Sws,
    unsigned short* __restrict__ Sout,
    unsigned short* __restrict__ Ssp)
{
  __shared__ unsigned short Al[2][128 * 64];
  __shared__ unsigned short Bl[2][128 * 64];

  const int bid = blockIdx.x;                 // 2112 = 8 x 264
  const int item = (bid & 7) * 264 + (bid >> 3);
  const int b = (item >= 1584) ? 3 : (item >= 1056) ? 2 : (item >= 528) ? 1 : 0;
  const int id = item - b * 528;
  const int ti = tri_row(id);
  const int tj = id - ti * (ti + 1) / 2;

  const unsigned short* Qb = Q + (size_t)b * SEQ * DIM;
  const unsigned short* Kb = K + (size_t)b * SEQ * DIM;

  const int tid = threadIdx.x, ln = tid & 63, wv = tid >> 6;
  const int l15 = ln & 15, quad = ln >> 4;
  const int mw = wv >> 1, nw = wv & 1;

  f32x4 acc[4][4] = {};
  gemm128_pipe(Qb + (size_t)(ti * 128) * DIM, DIM,
               Kb + (size_t)(tj * 128) * DIM, DIM, DIM / 64,
               Al, Bl, tid, mw, nw, l15, quad, acc);

  const int Lt = (ti + 1) << 7;
  unsigned short* base = s_base(b, ti, Sws, Sout, Ssp) +
                         (size_t)(ti * (ti + 1) / 2) * TSZ;
#pragma unroll
  for (int mi = 0; mi < 4; ++mi)
#pragma unroll
    for (int ni = 0; ni < 4; ++ni) {
      const int mloc = mw * 64 + mi * 16 + quad * 4;
      const int col  = tj * 128 + nw * 64 + ni * 16 + l15;
      unsigned short* p = base + (size_t)mloc * Lt + col;
#pragma unroll
      for (int r = 0; r < 4; ++r) p[(size_t)r * Lt] = f2h(acc[mi][ni][r]);
    }
}

// ---------------- row softmax: all 4 batches, one launch --------------------
__global__ __launch_bounds__(256) void sm_rows_p(
    unsigned short* __restrict__ Sws, unsigned short* __restrict__ Sout,
    unsigned short* __restrict__ Ssp)
{
  const int bid = blockIdx.x;      // 16384
  const int b = bid >> 12;
  const int r = bid & 4095;
  const int ti = r >> 7, ri = r & 127;
  const int Lt = (ti + 1) << 7;
  const int len = r + 1;
  unsigned short* row = s_base(b, ti, Sws, Sout, Ssp) +
                        (size_t)(ti * (ti + 1) / 2) * TSZ + (size_t)ri * Lt;
  const int t = threadIdx.x;
  __shared__ float red[8];

  float v[16];
#pragma unroll
  for (int it = 0; it < 2; ++it) {
    const int c = t * 8 + it * 2048;
    if (c < Lt) {
      u16x8 h = *(const u16x8*)(row + c);
#pragma unroll
      for (int i = 0; i < 8; ++i)
        v[it * 8 + i] = (c + i < len) ? h2f(h[i]) : -1e30f;
    } else {
#pragma unroll
      for (int i = 0; i < 8; ++i) v[it * 8 + i] = -1e30f;
    }
  }

  float mx = v[0];
#pragma unroll
  for (int i = 1; i < 16; ++i) mx = fmaxf(mx, v[i]);
#pragma unroll
  for (int off = 1; off < 64; off <<= 1) mx = fmaxf(mx, __shfl_xor(mx, off));
  if ((t & 63) == 0) red[t >> 6] = mx;
  __syncthreads();
  mx = fmaxf(fmaxf(red[0], red[1]), fmaxf(red[2], red[3]));

  float p[16];
  float sm = 0.f;
#pragma unroll
  for (int it = 0; it < 2; ++it) {
    const int c = t * 8 + it * 2048;
#pragma unroll
    for (int i = 0; i < 8; ++i) {
      const int k = it * 8 + i;
      p[k] = (c + i < len) ? __expf(v[k] - mx) : 0.f;
      sm += p[k];
    }
  }
#pragma unroll
  for (int off = 1; off < 64; off <<= 1) sm += __shfl_xor(sm, off);
  if ((t & 63) == 0) red[4 + (t >> 6)] = sm;
  __syncthreads();
  const float inv = 1.f / (red[4] + red[5] + red[6] + red[7]);

#pragma unroll
  for (int it = 0; it < 2; ++it) {
    const int c = t * 8 + it * 2048;
    if (c < Lt) {
      u16x8 o;
#pragma unroll
      for (int i = 0; i < 8; ++i) o[i] = f2bf(p[it * 8 + i] * inv);
      *(u16x8*)(row + c) = o;
    }
  }
}

// ---------------- O = P * V: 2 batches per launch (r4 structure) ------------
// 512 blocks = 2b x 8d x 32 ti; blocks j and j+256 complementary ti.
// S0/S1: per-batch bases; S1sp: base for (b=1, ti=31) spill case.
__global__ __launch_bounds__(256) void pv_gemm_p(
    const unsigned short* __restrict__ S0,
    const unsigned short* __restrict__ S1,
    const unsigned short* __restrict__ S1sp,
    const unsigned short* __restrict__ Vt,
    float* __restrict__ Ob)
{
  __shared__ unsigned short Al[2][128 * 64];
  __shared__ unsigned short Bl[2][128 * 64];

  const int bid = blockIdx.x;                 // 512
  const int d = bid & 7;
  const int rr_ = bid >> 3;                   // 0..63
  const int b = rr_ & 1;
  const int q = rr_ >> 1;                     // 0..31
  const int ti = (q & 16) ? (31 - (q & 15)) : q;
  const int Lt = (ti + 1) << 7;

  const unsigned short* Sbase = b ? ((ti == 31) ? S1sp : S1) : S0;
  const unsigned short* Sb = Sbase + (size_t)(ti * (ti + 1) / 2) * TSZ;
  const unsigned short* Vb = Vt + (size_t)b * ((size_t)DIM * SEQ) +
                             (size_t)(d * 128) * SEQ;
  float* Outb = Ob + (size_t)b * ((size_t)SEQ * DIM);

  const int tid = threadIdx.x, ln = tid & 63, wv = tid >> 6;
  const int l15 = ln & 15, quad = ln >> 4;
  const int mw = wv >> 1, nw = wv & 1;

  f32x4 acc[4][4] = {};
  gemm128_pipe(Sb, Lt, Vb, SEQ, Lt / 64, Al, Bl, tid, mw, nw, l15, quad, acc);

#pragma unroll
  for (int mi = 0; mi < 4; ++mi)
#pragma unroll
    for (int ni = 0; ni < 4; ++ni) {
      const int m = ti * 128 + mw * 64 + mi * 16 + quad * 4;
      const int e = d * 128 + nw * 64 + ni * 16 + l15;
      float* pp = Outb + (size_t)m * DIM + e;
#pragma unroll
      for (int r = 0; r < 4; ++r) pp[(size_t)r * DIM] = acc[mi][ni][r];
    }
}

extern "C" void kernel_launch(void* const* d_in, const int* in_sizes, int n_in,
                              void* d_out, int out_size, void* d_ws, size_t ws_size,
                              hipStream_t stream) {
  const float* x  = (const float*)d_in[0];
  const float* Wq = (const float*)d_in[1];
  const float* Wk = (const float*)d_in[2];
  const float* Wv = (const float*)d_in[3];
  float* out = (float*)d_out;

  // ws layout (134.25 MB):
  //   [0,32MB):  xb (bf16 x)   [32,38MB): Wb (bf16 weights)
  //     -> after qkv both dead; S[b0],S[b1] at ws[0,33MB), b3-TI31 spill at
  //        ws[33,34MB).
  //   [38,70MB): Q   [70,102MB): K   [102,134MB): Vt
  // out (64MB) doubles as S scratch for b2,b3 before pv writes it:
  //   S[b2] = out[0,16.5MB), S[b3] = out[16.5,32MB) + spill.
  // pv order: pvA (b2,b3) reads out[0,32)+spill, writes out[32,64);
  //           pvB (b0,b1) reads ws[0,33)+spill-region-free, writes out[0,32).
  char* wsb = (char*)d_ws;
  unsigned short* xb = (unsigned short*)wsb;
  unsigned short* Wb = (unsigned short*)(wsb + (32u << 20));
  unsigned short* Qb = (unsigned short*)(wsb + (38u << 20));
  unsigned short* Sws  = xb;
  unsigned short* Sout = (unsigned short*)out;
  // pre-adjusted: Ssp + tri(31)*TSZ == wsb + 33MiB
  unsigned short* Ssp = (unsigned short*)(wsb + (33u << 20)) - (size_t)496 * TSZ;

  conv_all<<<9728, 256, 0, stream>>>(x, Wq, Wk, Wv, xb, Wb);

  qkv_gemm5<<<256, 1024, 0, stream>>>(xb, Wb, Qb);

  const size_t n = (size_t)MTOT * DIM;
  const unsigned short* Kb = Qb + n;
  const unsigned short* Vt = Qb + 2 * n;

  qk_gemm_p<<<2112, 256, 0, stream>>>(Qb, Kb, Sws, Sout, Ssp);
  sm_rows_p<<<16384, 256, 0, stream>>>(Sws, Sout, Ssp);

  // pvA: batches 2,3 (S in out[0,32MB) + spill), writes out[32,64MB)
  pv_gemm_p<<<512, 256, 0, stream>>>(
      Sout, Sout + PSIZE, Ssp,
      Vt + (size_t)2 * DIM * SEQ, out + (size_t)2 * SEQ * DIM);
  // pvB: batches 0,1 (S in ws), writes out[0,32MB)
  pv_gemm_p<<<512, 256, 0, stream>>>(
      Sws, Sws + PSIZE, Sws + PSIZE,
      Vt, out);
}

// Round 9
// 497.929 us; speedup vs baseline: 4.1253x; 4.1253x over previous
//
#include <hip/hip_runtime.h>
#include <hip/hip_bf16.h>

typedef __attribute__((ext_vector_type(8))) short bf16x8;
typedef __attribute__((ext_vector_type(4))) float f32x4;
typedef __attribute__((ext_vector_type(4))) unsigned short u16x4;
typedef __attribute__((ext_vector_type(8))) unsigned short u16x8;

#define SEQ   4096
#define DIM   1024
#define MTOT  16384
#define NTILE 32            // SEQ/128 query tiles (128-granular packing)
#define NTRI  528           // causal 128-tiles per batch
#define TSZ   16384         // elems per 128x128 tile
#define PSIZE ((size_t)NTRI * TSZ)   // 16.5 MiB per batch (u16)

#define AS1 __attribute__((address_space(1)))
#define AS3 __attribute__((address_space(3)))

static __device__ __forceinline__ unsigned short f2bf(float f) {
  union { float f; unsigned u; } v; v.f = f;
  unsigned r = v.u + 0x7FFFu + ((v.u >> 16) & 1u);
  return (unsigned short)(r >> 16);
}

static __device__ __forceinline__ unsigned short f2h(float f) {
  union { _Float16 h; unsigned short u; } v; v.h = (_Float16)f; return v.u;
}

static __device__ __forceinline__ float h2f(unsigned short u) {
  union { unsigned short u; _Float16 h; } v; v.u = u; return (float)v.h;
}

static __device__ __forceinline__ bf16x8 pack8(f32x4 a, f32x4 b) {
  bf16x8 v;
  v[0]=(short)f2bf(a[0]); v[1]=(short)f2bf(a[1]);
  v[2]=(short)f2bf(a[2]); v[3]=(short)f2bf(a[3]);
  v[4]=(short)f2bf(b[0]); v[5]=(short)f2bf(b[1]);
  v[6]=(short)f2bf(b[2]); v[7]=(short)f2bf(b[3]);
  return v;
}

static __device__ __forceinline__ int tri_row(int id) {
  int ti = (int)((sqrtf(8.f * (float)id + 1.f) - 1.f) * 0.5f);
  while ((ti + 1) * (ti + 2) / 2 <= id) ++ti;
  while (ti * (ti + 1) / 2 > id) --ti;
  return ti;
}

// ---------------- fused fp32 -> bf16 preconvert (x + all 3 weights) ---------
__global__ __launch_bounds__(256) void conv_all(
    const float* __restrict__ x,
    const float* __restrict__ Wq, const float* __restrict__ Wk,
    const float* __restrict__ Wv,
    unsigned short* __restrict__ xb, unsigned short* __restrict__ Wb)
{
  const int bid = blockIdx.x;
  if (bid < 8192) {
    const int i = bid * 256 + threadIdx.x;      // x: 2097152 vec8
    const f32x4* s = (const f32x4*)(x + (size_t)i * 8);
    f32x4 a = s[0], b = s[1];
    *(bf16x8*)(xb + (size_t)i * 8) = pack8(a, b);
  } else {
    const int i = (bid - 8192) * 256 + threadIdx.x;   // weights: 393216 vec8
    const int seg = i >> 17;
    const int loc = i & 131071;
    const float* src = (seg == 0) ? Wq : (seg == 1) ? Wk : Wv;
    const float scale = (seg == 0) ? 0.03125f : 1.0f;  // fold 1/sqrt(D) into Wq
    const f32x4* s = (const f32x4*)(src + (size_t)loc * 8);
    f32x4 a = s[0], b = s[1];
#pragma unroll
    for (int r = 0; r < 4; ++r) { a[r] *= scale; b[r] *= scale; }
    *(bf16x8*)(Wb + (size_t)i * 8) = pack8(a, b);
  }
}

// ---------------- counted-vmcnt heads ----------------
static __device__ __forceinline__ void head_n4(bool more) {
  if (more) asm volatile("s_waitcnt vmcnt(4)" ::: "memory");
  else      asm volatile("s_waitcnt vmcnt(0)" ::: "memory");
  __builtin_amdgcn_s_barrier();
  asm volatile("" ::: "memory");
}
static __device__ __forceinline__ void head_n8(bool more) {
  if (more) asm volatile("s_waitcnt vmcnt(8)" ::: "memory");
  else      asm volatile("s_waitcnt vmcnt(0)" ::: "memory");
  __builtin_amdgcn_s_barrier();
  asm volatile("" ::: "memory");
}
static __device__ __forceinline__ void tail_bar() {
  asm volatile("" ::: "memory");
  __builtin_amdgcn_s_barrier();
  asm volatile("" ::: "memory");
}

// ============================================================================
// QKV: 256x256 tile, 1024 thr / 16 waves (4x4), BK=64 (r6/r7 structure,
// verified 135us / MfmaUtil 32% / conflicts 0). Single MFMA operand order.
// ============================================================================
static __device__ __forceinline__ void stage64(
    const unsigned short* __restrict__ g, int ld, unsigned short* dst, int tid)
{
  const int w = tid >> 6, ln = tid & 63;
#pragma unroll
  for (int l = 0; l < 2; ++l) {
    const int row = l * 128 + w * 8 + (ln >> 3);
    const int grp = (ln & 7) ^ (row & 7);
    __builtin_amdgcn_global_load_lds(
        (const AS1 void*)(g + (size_t)row * ld + grp * 8),
        (AS3 void*)&dst[(l * 128 + w * 8) * 64], 16, 0, 0);
  }
}

static __device__ __forceinline__ void compute64(
    const unsigned short* Au, const unsigned short* Bu,
    int wr, int wc, int l15, int quad, f32x4 (&acc)[4][4])
{
#pragma unroll
  for (int ks = 0; ks < 2; ++ks) {
    bf16x8 af[4], bq[4];
#pragma unroll
    for (int i = 0; i < 4; ++i) {
      const int ar = wr * 64 + i * 16 + l15;
      af[i] = *(const bf16x8*)&Au[ar * 64 + (((ks * 4 + quad) ^ (ar & 7)) * 8)];
      const int br = wc * 64 + i * 16 + l15;
      bq[i] = *(const bf16x8*)&Bu[br * 64 + (((ks * 4 + quad) ^ (br & 7)) * 8)];
    }
    __builtin_amdgcn_s_setprio(1);
#pragma unroll
    for (int i = 0; i < 4; ++i)
#pragma unroll
      for (int j = 0; j < 4; ++j)
        acc[i][j] = __builtin_amdgcn_mfma_f32_16x16x32_bf16(af[i], bq[j], acc[i][j], 0, 0, 0);
    __builtin_amdgcn_s_setprio(0);
  }
}

__global__ __launch_bounds__(1024, 4) void qkv_gemm5(
    const unsigned short* __restrict__ xb,
    const unsigned short* __restrict__ Wb,
    unsigned short* __restrict__ outQ)
{
  __shared__ unsigned short As[2][256 * 64];
  __shared__ unsigned short Bs[2][256 * 64];

  const int bid = blockIdx.x;               // 256
  const int xcd = bid & 7, i = bid >> 3;
  const int mt = xcd * 8 + (i >> 2);        // A-panel locality per XCD
  const int nt = i & 3;
  const int m0 = mt * 256, n0 = nt * 256;

  const int tid = threadIdx.x;
  const int w = tid >> 6, ln = tid & 63;
  const int l15 = ln & 15, quad = ln >> 4;
  const int wr = w >> 2, wc = w & 3;

  const unsigned short* Abase = xb + (size_t)m0 * DIM;
  auto gA = [&](int v) { return Abase + (v & 15) * 64; };
  auto gB = [&](int v) {
    return Wb + (size_t)(v >> 4) * (DIM * DIM) + (size_t)n0 * DIM + (v & 15) * 64;
  };

  f32x4 acc[4][4] = {};

  stage64(gA(0), DIM, As[0], tid);
  stage64(gB(0), DIM, Bs[0], tid);
  stage64(gA(1), DIM, As[1], tid);
  stage64(gB(1), DIM, Bs[1], tid);

#pragma unroll 1
  for (int v = 0; v < 48; ++v) {
    const int p = v & 1;
    head_n4(v + 1 < 48);
    compute64(As[p], Bs[p], wr, wc, l15, quad, acc);
    tail_bar();

    if ((v & 15) == 15) {
      const int z = v >> 4;
      unsigned short* outb = outQ + (size_t)z * ((size_t)MTOT * DIM);
      if (z < 2) {
#pragma unroll
        for (int fm = 0; fm < 4; ++fm)
#pragma unroll
          for (int fn = 0; fn < 4; ++fn) {
            const int m = m0 + wr * 64 + fm * 16 + quad * 4;
            const int e = n0 + wc * 64 + fn * 16 + l15;
            unsigned short* pp = outb + (size_t)m * DIM + e;
#pragma unroll
            for (int r = 0; r < 4; ++r) pp[(size_t)r * DIM] = f2bf(acc[fm][fn][r]);
          }
      } else {
#pragma unroll
        for (int fm = 0; fm < 4; ++fm)
#pragma unroll
          for (int fn = 0; fn < 4; ++fn) {
            const int m = m0 + wr * 64 + fm * 16 + quad * 4;   // s index
            const int e = n0 + wc * 64 + fn * 16 + l15;        // dim index
            const int bb = m >> 12, ss = m & 4095;
            u16x4 v4;
#pragma unroll
            for (int r = 0; r < 4; ++r) v4[r] = f2bf(acc[fm][fn][r]);
            *(u16x4*)(outb + ((size_t)bb * DIM + e) * SEQ + ss) = v4;
          }
      }
#pragma unroll
      for (int fm = 0; fm < 4; ++fm)
#pragma unroll
        for (int fn = 0; fn < 4; ++fn) acc[fm][fn] = (f32x4){0.f, 0.f, 0.f, 0.f};
    }

    if (v + 2 < 48) {
      stage64(gA(v + 2), DIM, As[p], tid);
      stage64(gB(v + 2), DIM, Bs[p], tid);
    }
  }
}

// ============================================================================
// 128x128-tile core, BK=64, counted-vmcnt double buffer (r4-verified).
// LDS 64 KiB -> 2 blocks/CU.
// ============================================================================
static __device__ __forceinline__ void stage128(
    const unsigned short* __restrict__ Ab, int lda,
    const unsigned short* __restrict__ Bb, int ldb,
    unsigned short* Al, unsigned short* Bl, int tid)
{
  const int wv = tid >> 6, ln = tid & 63;
  const int lrow = ln >> 3, lcol = (ln & 7) * 8;
#pragma unroll
  for (int r = 0; r < 4; ++r) {
    const int row = (wv * 4 + r) * 8 + lrow;
    const int sw = ((row >> 2) & 3) << 4;
    __builtin_amdgcn_global_load_lds(
        (const AS1 void*)(Ab + (size_t)row * lda + (lcol ^ sw)),
        (AS3 void*)&Al[(wv * 4 + r) * 512], 16, 0, 0);
    __builtin_amdgcn_global_load_lds(
        (const AS1 void*)(Bb + (size_t)row * ldb + (lcol ^ sw)),
        (AS3 void*)&Bl[(wv * 4 + r) * 512], 16, 0, 0);
  }
}

static __device__ __forceinline__ void compute128(
    const unsigned short* Al, const unsigned short* Bl,
    int mw, int nw, int l15, int quad, f32x4 (&acc)[4][4])
{
  const int csw = (l15 >> 2) << 4;
#pragma unroll
  for (int ks = 0; ks < 2; ++ks) {
    bf16x8 af[4], bfr[4];
#pragma unroll
    for (int i = 0; i < 4; ++i) {
      af[i]  = *(const bf16x8*)&Al[(mw * 64 + i * 16 + l15) * 64 + ((ks * 32 + quad * 8) ^ csw)];
      bfr[i] = *(const bf16x8*)&Bl[(nw * 64 + i * 16 + l15) * 64 + ((ks * 32 + quad * 8) ^ csw)];
    }
    __builtin_amdgcn_s_setprio(1);
#pragma unroll
    for (int mi = 0; mi < 4; ++mi)
#pragma unroll
      for (int ni = 0; ni < 4; ++ni)
        acc[mi][ni] = __builtin_amdgcn_mfma_f32_16x16x32_bf16(af[mi], bfr[ni], acc[mi][ni], 0, 0, 0);
    __builtin_amdgcn_s_setprio(0);
  }
}

static __device__ __forceinline__ void gemm128_pipe(
    const unsigned short* __restrict__ Ab, int lda,
    const unsigned short* __restrict__ Bb, int ldb, int nt,
    unsigned short (*Al)[128 * 64], unsigned short (*Bl)[128 * 64],
    int tid, int mw, int nw, int l15, int quad, f32x4 (&acc)[4][4])
{
  stage128(Ab, lda, Bb, ldb, Al[0], Bl[0], tid);
  if (nt > 1) stage128(Ab + 64, lda, Bb + 64, ldb, Al[1], Bl[1], tid);
#pragma unroll 1
  for (int v = 0; v < nt; ++v) {
    const int p = v & 1;
    head_n8(v + 1 < nt);
    compute128(Al[p], Bl[p], mw, nw, l15, quad, acc);
    tail_bar();
    if (v + 2 < nt)
      stage128(Ab + (v + 2) * 64, lda, Bb + (v + 2) * 64, ldb, Al[p], Bl[p], tid);
  }
}

// S base per (batch, tile-row).  S[b0],S[b1] in ws[0,33MiB); S[b2] in
// out[0,16.5MiB); S[b3] in out[16.5,32MiB) except TI=31 which spills to
// ws[33,34MiB) (dead Wb space).  Ssp is pre-adjusted so Ssp+tri(31)*TSZ
// lands at the spill region.
static __device__ __forceinline__ unsigned short* s_base(
    int b, int ti, unsigned short* Sws, unsigned short* Sout,
    unsigned short* Ssp)
{
  unsigned short* base = (b == 0) ? Sws
                       : (b == 1) ? (Sws + PSIZE)
                       : (b == 2) ? Sout : (Sout + PSIZE);
  if (b == 3 && ti == 31) base = Ssp;
  return base;
}

// ---------------- S = Q K^T: all 4 batches, one launch ----------------------
// 2112 blocks = 8 XCD x 264. Uniform K=1024 per block.
__global__ __launch_bounds__(256) void qk_gemm_p(
    const unsigned short* __restrict__ Q,
    const unsigned short* __restrict__ K,
    unsigned short* __restrict__ Sws,
    unsigned short* __restrict__ Sout,
    unsigned short* __restrict__ Ssp)
{
  __shared__ unsigned short Al[2][128 * 64];
  __shared__ unsigned short Bl[2][128 * 64];

  const int bid = blockIdx.x;                 // 2112 = 8 x 264
  const int item = (bid & 7) * 264 + (bid >> 3);
  const int b = (item >= 1584) ? 3 : (item >= 1056) ? 2 : (item >= 528) ? 1 : 0;
  const int id = item - b * 528;
  const int ti = tri_row(id);
  const int tj = id - ti * (ti + 1) / 2;

  const unsigned short* Qb = Q + (size_t)b * SEQ * DIM;
  const unsigned short* Kb = K + (size_t)b * SEQ * DIM;

  const int tid = threadIdx.x, ln = tid & 63, wv = tid >> 6;
  const int l15 = ln & 15, quad = ln >> 4;
  const int mw = wv >> 1, nw = wv & 1;

  f32x4 acc[4][4] = {};
  gemm128_pipe(Qb + (size_t)(ti * 128) * DIM, DIM,
               Kb + (size_t)(tj * 128) * DIM, DIM, DIM / 64,
               Al, Bl, tid, mw, nw, l15, quad, acc);

  const int Lt = (ti + 1) << 7;
  unsigned short* base = s_base(b, ti, Sws, Sout, Ssp) +
                         (size_t)(ti * (ti + 1) / 2) * TSZ;
#pragma unroll
  for (int mi = 0; mi < 4; ++mi)
#pragma unroll
    for (int ni = 0; ni < 4; ++ni) {
      const int mloc = mw * 64 + mi * 16 + quad * 4;
      const int col  = tj * 128 + nw * 64 + ni * 16 + l15;
      unsigned short* p = base + (size_t)mloc * Lt + col;
#pragma unroll
      for (int r = 0; r < 4; ++r) p[(size_t)r * Lt] = f2h(acc[mi][ni][r]);
    }
}

// ---------------- row softmax: all 4 batches, one launch --------------------
__global__ __launch_bounds__(256) void sm_rows_p(
    unsigned short* __restrict__ Sws, unsigned short* __restrict__ Sout,
    unsigned short* __restrict__ Ssp)
{
  const int bid = blockIdx.x;      // 16384
  const int b = bid >> 12;
  const int r = bid & 4095;
  const int ti = r >> 7, ri = r & 127;
  const int Lt = (ti + 1) << 7;
  const int len = r + 1;
  unsigned short* row = s_base(b, ti, Sws, Sout, Ssp) +
                        (size_t)(ti * (ti + 1) / 2) * TSZ + (size_t)ri * Lt;
  const int t = threadIdx.x;
  __shared__ float red[8];

  float v[16];
#pragma unroll
  for (int it = 0; it < 2; ++it) {
    const int c = t * 8 + it * 2048;
    if (c < Lt) {
      u16x8 h = *(const u16x8*)(row + c);
#pragma unroll
      for (int i = 0; i < 8; ++i)
        v[it * 8 + i] = (c + i < len) ? h2f(h[i]) : -1e30f;
    } else {
#pragma unroll
      for (int i = 0; i < 8; ++i) v[it * 8 + i] = -1e30f;
    }
  }

  float mx = v[0];
#pragma unroll
  for (int i = 1; i < 16; ++i) mx = fmaxf(mx, v[i]);
#pragma unroll
  for (int off = 1; off < 64; off <<= 1) mx = fmaxf(mx, __shfl_xor(mx, off));
  if ((t & 63) == 0) red[t >> 6] = mx;
  __syncthreads();
  mx = fmaxf(fmaxf(red[0], red[1]), fmaxf(red[2], red[3]));

  float p[16];
  float sm = 0.f;
#pragma unroll
  for (int it = 0; it < 2; ++it) {
    const int c = t * 8 + it * 2048;
#pragma unroll
    for (int i = 0; i < 8; ++i) {
      const int k = it * 8 + i;
      p[k] = (c + i < len) ? __expf(v[k] - mx) : 0.f;
      sm += p[k];
    }
  }
#pragma unroll
  for (int off = 1; off < 64; off <<= 1) sm += __shfl_xor(sm, off);
  if ((t & 63) == 0) red[4 + (t >> 6)] = sm;
  __syncthreads();
  const float inv = 1.f / (red[4] + red[5] + red[6] + red[7]);

#pragma unroll
  for (int it = 0; it < 2; ++it) {
    const int c = t * 8 + it * 2048;
    if (c < Lt) {
      u16x8 o;
#pragma unroll
      for (int i = 0; i < 8; ++i) o[i] = f2bf(p[it * 8 + i] * inv);
      *(u16x8*)(row + c) = o;
    }
  }
}

// ---------------- O = P * V: 2 batches per launch (r4 structure) ------------
// 512 blocks = 2b x 8d x 32 ti; blocks j and j+256 complementary ti.
// S0/S1: per-batch bases; S1sp: base for (b=1, ti=31) spill case.
__global__ __launch_bounds__(256) void pv_gemm_p(
    const unsigned short* __restrict__ S0,
    const unsigned short* __restrict__ S1,
    const unsigned short* __restrict__ S1sp,
    const unsigned short* __restrict__ Vt,
    float* __restrict__ Ob)
{
  __shared__ unsigned short Al[2][128 * 64];
  __shared__ unsigned short Bl[2][128 * 64];

  const int bid = blockIdx.x;                 // 512
  const int d = bid & 7;
  const int rr_ = bid >> 3;                   // 0..63
  const int b = rr_ & 1;
  const int q = rr_ >> 1;                     // 0..31
  const int ti = (q & 16) ? (31 - (q & 15)) : q;
  const int Lt = (ti + 1) << 7;

  const unsigned short* Sbase = b ? ((ti == 31) ? S1sp : S1) : S0;
  const unsigned short* Sb = Sbase + (size_t)(ti * (ti + 1) / 2) * TSZ;
  const unsigned short* Vb = Vt + (size_t)b * ((size_t)DIM * SEQ) +
                             (size_t)(d * 128) * SEQ;
  float* Outb = Ob + (size_t)b * ((size_t)SEQ * DIM);

  const int tid = threadIdx.x, ln = tid & 63, wv = tid >> 6;
  const int l15 = ln & 15, quad = ln >> 4;
  const int mw = wv >> 1, nw = wv & 1;

  f32x4 acc[4][4] = {};
  gemm128_pipe(Sb, Lt, Vb, SEQ, Lt / 64, Al, Bl, tid, mw, nw, l15, quad, acc);

#pragma unroll
  for (int mi = 0; mi < 4; ++mi)
#pragma unroll
    for (int ni = 0; ni < 4; ++ni) {
      const int m = ti * 128 + mw * 64 + mi * 16 + quad * 4;
      const int e = d * 128 + nw * 64 + ni * 16 + l15;
      float* pp = Outb + (size_t)m * DIM + e;
#pragma unroll
      for (int r = 0; r < 4; ++r) pp[(size_t)r * DIM] = acc[mi][ni][r];
    }
}

extern "C" void kernel_launch(void* const* d_in, const int* in_sizes, int n_in,
                              void* d_out, int out_size, void* d_ws, size_t ws_size,
                              hipStream_t stream) {
  const float* x  = (const float*)d_in[0];
  const float* Wq = (const float*)d_in[1];
  const float* Wk = (const float*)d_in[2];
  const float* Wv = (const float*)d_in[3];
  float* out = (float*)d_out;

  // ws layout (134.25 MB):
  //   [0,32MB):  xb (bf16 x)   [32,38MB): Wb (bf16 weights)
  //     -> after qkv both dead; S[b0],S[b1] at ws[0,33MB), b3-TI31 spill at
  //        ws[33,34MB).
  //   [38,70MB): Q   [70,102MB): K   [102,134MB): Vt
  // out (64MB) doubles as S scratch for b2,b3 before pv writes it:
  //   S[b2] = out[0,16.5MB), S[b3] = out[16.5,32MB) + spill.
  // pv order: pvA (b2,b3) reads out[0,32)+spill, writes out[32,64);
  //           pvB (b0,b1) reads ws[0,33), writes out[0,32).
  char* wsb = (char*)d_ws;
  unsigned short* xb = (unsigned short*)wsb;
  unsigned short* Wb = (unsigned short*)(wsb + (32u << 20));
  unsigned short* Qb = (unsigned short*)(wsb + (38u << 20));
  unsigned short* Sws  = xb;
  unsigned short* Sout = (unsigned short*)out;
  // pre-adjusted: Ssp + tri(31)*TSZ == wsb + 33MiB
  unsigned short* Ssp = (unsigned short*)(wsb + (33u << 20)) - (size_t)496 * TSZ;

  conv_all<<<9728, 256, 0, stream>>>(x, Wq, Wk, Wv, xb, Wb);

  qkv_gemm5<<<256, 1024, 0, stream>>>(xb, Wb, Qb);

  const size_t n = (size_t)MTOT * DIM;
  const unsigned short* Kb = Qb + n;
  const unsigned short* Vt = Qb + 2 * n;

  qk_gemm_p<<<2112, 256, 0, stream>>>(Qb, Kb, Sws, Sout, Ssp);
  sm_rows_p<<<16384, 256, 0, stream>>>(Sws, Sout, Ssp);

  // pvA: batches 2,3 (S in out[0,32MB) + spill), writes out[32,64MB)
  pv_gemm_p<<<512, 256, 0, stream>>>(
      Sout, Sout + PSIZE, Ssp,
      Vt + (size_t)2 * DIM * SEQ, out + (size_t)2 * SEQ * DIM);
  // pvB: batches 0,1 (S in ws), writes out[0,32MB)
  pv_gemm_p<<<512, 256, 0, stream>>>(
      Sws, Sws + PSIZE, Sws + PSIZE,
      Vt, out);
}